// Round 1
// baseline (14345.564 us; speedup 1.0000x reference)
//
#include <hip/hip_runtime.h>
#include <hip/hip_bf16.h>

#define C 64  // channels

// ---------------------------------------------------------------------------
// Fused MLP: h0 = relu(relu(x @ W1) @ W2)
// x: [nN, 512], W1: [512, 64], W2: [64, 64], h0: [nN, 64]
// One block computes 64 rows. 256 threads, 4x4 microtile per thread.
// ---------------------------------------------------------------------------
__launch_bounds__(256)
__global__ void mlp_kernel(const float* __restrict__ x,
                           const float* __restrict__ W1,
                           const float* __restrict__ W2,
                           float* __restrict__ h0, int nN)
{
    __shared__ float As[32][68];  // A tile transposed: As[k][row]
    __shared__ float Bs[32][68];  // W1 tile: Bs[k][col]
    __shared__ float Hs[64][68];  // h1 transposed: Hs[k][row]
    __shared__ float Ws[64][68];  // W2: Ws[k][col]

    const int t  = threadIdx.x;
    const int ty = t >> 4;          // 0..15 -> rows 4*ty..4*ty+3
    const int tx = t & 15;          // 0..15 -> cols 4*tx..4*tx+3
    const int row0 = blockIdx.x * 64;

    float acc[4][4] = {};

    // ---- layer 1: K = 512, BK = 32 ----
    const int lr = t >> 3;          // 0..31 (row within half-tile)
    const int lk = (t & 7) * 4;     // k offset 0,4,...,28

    for (int k0 = 0; k0 < 512; k0 += 32) {
        // load A tile (64 rows x 32 k), transposed into As[k][row]
        #pragma unroll
        for (int half = 0; half < 2; ++half) {
            int r = lr + 32 * half;
            int grow = row0 + r;
            float4 v = make_float4(0.f, 0.f, 0.f, 0.f);
            if (grow < nN)
                v = *(const float4*)&x[(size_t)grow * 512 + k0 + lk];
            As[lk + 0][r] = v.x;
            As[lk + 1][r] = v.y;
            As[lk + 2][r] = v.z;
            As[lk + 3][r] = v.w;
        }
        // load B tile (32 k x 64 cols)
        {
            int kb = t >> 4;        // 0..15
            int c4 = (t & 15) * 4;
            #pragma unroll
            for (int half = 0; half < 2; ++half) {
                int k = kb + 16 * half;
                float4 w = *(const float4*)&W1[(size_t)(k0 + k) * 64 + c4];
                *(float4*)&Bs[k][c4] = w;
            }
        }
        __syncthreads();
        #pragma unroll
        for (int kk = 0; kk < 32; ++kk) {
            float4 a = *(float4*)&As[kk][ty * 4];
            float4 b = *(float4*)&Bs[kk][tx * 4];
            float av[4] = {a.x, a.y, a.z, a.w};
            float bv[4] = {b.x, b.y, b.z, b.w};
            #pragma unroll
            for (int i = 0; i < 4; ++i)
                #pragma unroll
                for (int j = 0; j < 4; ++j)
                    acc[i][j] += av[i] * bv[j];
        }
        __syncthreads();
    }

    // relu + store h1 transposed into Hs[k][row]
    #pragma unroll
    for (int i = 0; i < 4; ++i)
        #pragma unroll
        for (int j = 0; j < 4; ++j) {
            float v = acc[i][j];
            Hs[tx * 4 + j][ty * 4 + i] = v > 0.f ? v : 0.f;
        }

    // load W2 into Ws
    {
        int kb = t >> 4;
        int c4 = (t & 15) * 4;
        #pragma unroll
        for (int q = 0; q < 4; ++q) {
            int k = kb + 16 * q;
            *(float4*)&Ws[k][c4] = *(const float4*)&W2[(size_t)k * 64 + c4];
        }
    }
    __syncthreads();

    // ---- layer 2: K = 64 ----
    float acc2[4][4] = {};
    #pragma unroll
    for (int kk = 0; kk < 64; ++kk) {
        float4 a = *(float4*)&Hs[kk][ty * 4];
        float4 b = *(float4*)&Ws[kk][tx * 4];
        float av[4] = {a.x, a.y, a.z, a.w};
        float bv[4] = {b.x, b.y, b.z, b.w};
        #pragma unroll
        for (int i = 0; i < 4; ++i)
            #pragma unroll
            for (int j = 0; j < 4; ++j)
                acc2[i][j] += av[i] * bv[j];
    }

    // relu + write out
    #pragma unroll
    for (int i = 0; i < 4; ++i) {
        int grow = row0 + ty * 4 + i;
        if (grow < nN) {
            float4 o;
            o.x = acc2[i][0] > 0.f ? acc2[i][0] : 0.f;
            o.y = acc2[i][1] > 0.f ? acc2[i][1] : 0.f;
            o.z = acc2[i][2] > 0.f ? acc2[i][2] : 0.f;
            o.w = acc2[i][3] > 0.f ? acc2[i][3] : 0.f;
            *(float4*)&h0[(size_t)grow * 64 + tx * 4] = o;
        }
    }
}

// ---------------------------------------------------------------------------
// Gate: acc (+)= sigmoid(h[node] . wp) * h[node].  One wave per node.
// ---------------------------------------------------------------------------
__launch_bounds__(256)
__global__ void gate_kernel(const float* __restrict__ h,
                            const float* __restrict__ wp,
                            float* __restrict__ acc, int nN, int init)
{
    int gid = blockIdx.x * 256 + threadIdx.x;
    int node = gid >> 6;
    int c = gid & 63;
    if (node >= nN) return;
    float v = h[gid];
    float s = v * wp[c];
    #pragma unroll
    for (int off = 32; off > 0; off >>= 1)
        s += __shfl_xor(s, off);
    float g = 1.f / (1.f + __expf(-s));
    float o = g * v;
    if (init) acc[gid] = o;
    else      acc[gid] += o;
}

// ---------------------------------------------------------------------------
// SpMM scatter: next[dst] += w * cur[src].  16 threads per edge, float4 each.
// ---------------------------------------------------------------------------
__launch_bounds__(256)
__global__ void scatter_kernel(const int* __restrict__ src,
                               const int* __restrict__ dst,
                               const float* __restrict__ w,
                               const float* __restrict__ cur,
                               float* __restrict__ next, int nE)
{
    int gid = blockIdx.x * 256 + threadIdx.x;
    int e = gid >> 4;
    if (e >= nE) return;
    int q = gid & 15;
    int s = src[e];
    int d = dst[e];
    float wt = w[e];
    float4 v = *(const float4*)&cur[(size_t)s * 64 + q * 4];
    float* np = &next[(size_t)d * 64 + q * 4];
    unsafeAtomicAdd(np + 0, wt * v.x);
    unsafeAtomicAdd(np + 1, wt * v.y);
    unsafeAtomicAdd(np + 2, wt * v.z);
    unsafeAtomicAdd(np + 3, wt * v.w);
}

// ---------------------------------------------------------------------------
// Gather requested nodes
// ---------------------------------------------------------------------------
__launch_bounds__(256)
__global__ void gather_kernel(const float* __restrict__ acc,
                              const int* __restrict__ idx,
                              float* __restrict__ out, int nI)
{
    int gid = blockIdx.x * 256 + threadIdx.x;
    if (gid >= nI * 64) return;
    int i = gid >> 6;
    int c = gid & 63;
    out[gid] = acc[(size_t)idx[i] * 64 + c];
}

extern "C" void kernel_launch(void* const* d_in, const int* in_sizes, int n_in,
                              void* d_out, int out_size, void* d_ws, size_t ws_size,
                              hipStream_t stream) {
    const float* x    = (const float*)d_in[0];
    const int*   esrc = (const int*)d_in[1];
    const int*   edst = (const int*)d_in[2];
    const float* ew   = (const float*)d_in[3];
    const int*   nidx = (const int*)d_in[4];
    const float* W1   = (const float*)d_in[5];
    const float* W2   = (const float*)d_in[6];
    const float* wp   = (const float*)d_in[7];
    float* out = (float*)d_out;

    const int nN = in_sizes[0] / 512;
    const int nE = in_sizes[1];
    const int nI = in_sizes[4];

    float* bufA = (float*)d_ws;
    float* bufB = bufA + (size_t)nN * C;
    float* acc  = bufB + (size_t)nN * C;

    // h0 = relu(relu(x@W1)@W2)
    mlp_kernel<<<(nN + 63) / 64, 256, 0, stream>>>(x, W1, W2, bufA, nN);

    // hop 0 gate (init accumulator)
    gate_kernel<<<(nN * C + 255) / 256, 256, 0, stream>>>(bufA, wp, acc, nN, 1);

    float* cur = bufA;
    float* nxt = bufB;
    for (int k = 0; k < 10; ++k) {
        hipMemsetAsync(nxt, 0, (size_t)nN * C * sizeof(float), stream);
        scatter_kernel<<<(nE * 16 + 255) / 256, 256, 0, stream>>>(
            esrc, edst, ew, cur, nxt, nE);
        gate_kernel<<<(nN * C + 255) / 256, 256, 0, stream>>>(nxt, wp, acc, nN, 0);
        float* tmp = cur; cur = nxt; nxt = tmp;
    }

    gather_kernel<<<(nI * 64 + 255) / 256, 256, 0, stream>>>(acc, nidx, out, nI);
}

// Round 2
// 1598.047 us; speedup vs baseline: 8.9769x; 8.9769x over previous
//
#include <hip/hip_runtime.h>
#include <hip/hip_bf16.h>

#define C 64  // channels

// ---------------------------------------------------------------------------
// Fused MLP: h0 = relu(relu(x @ W1) @ W2)
// ---------------------------------------------------------------------------
__launch_bounds__(256)
__global__ void mlp_kernel(const float* __restrict__ x,
                           const float* __restrict__ W1,
                           const float* __restrict__ W2,
                           float* __restrict__ h0, int nN)
{
    __shared__ float As[32][68];  // A tile transposed: As[k][row]
    __shared__ float Bs[32][68];  // W1 tile: Bs[k][col]
    __shared__ float Hs[64][68];  // h1 transposed: Hs[k][row]
    __shared__ float Ws[64][68];  // W2: Ws[k][col]

    const int t  = threadIdx.x;
    const int ty = t >> 4;
    const int tx = t & 15;
    const int row0 = blockIdx.x * 64;

    float acc[4][4] = {};

    const int lr = t >> 3;
    const int lk = (t & 7) * 4;

    for (int k0 = 0; k0 < 512; k0 += 32) {
        #pragma unroll
        for (int half = 0; half < 2; ++half) {
            int r = lr + 32 * half;
            int grow = row0 + r;
            float4 v = make_float4(0.f, 0.f, 0.f, 0.f);
            if (grow < nN)
                v = *(const float4*)&x[(size_t)grow * 512 + k0 + lk];
            As[lk + 0][r] = v.x;
            As[lk + 1][r] = v.y;
            As[lk + 2][r] = v.z;
            As[lk + 3][r] = v.w;
        }
        {
            int kb = t >> 4;
            int c4 = (t & 15) * 4;
            #pragma unroll
            for (int half = 0; half < 2; ++half) {
                int k = kb + 16 * half;
                float4 w = *(const float4*)&W1[(size_t)(k0 + k) * 64 + c4];
                *(float4*)&Bs[k][c4] = w;
            }
        }
        __syncthreads();
        #pragma unroll
        for (int kk = 0; kk < 32; ++kk) {
            float4 a = *(float4*)&As[kk][ty * 4];
            float4 b = *(float4*)&Bs[kk][tx * 4];
            float av[4] = {a.x, a.y, a.z, a.w};
            float bv[4] = {b.x, b.y, b.z, b.w};
            #pragma unroll
            for (int i = 0; i < 4; ++i)
                #pragma unroll
                for (int j = 0; j < 4; ++j)
                    acc[i][j] += av[i] * bv[j];
        }
        __syncthreads();
    }

    #pragma unroll
    for (int i = 0; i < 4; ++i)
        #pragma unroll
        for (int j = 0; j < 4; ++j) {
            float v = acc[i][j];
            Hs[tx * 4 + j][ty * 4 + i] = v > 0.f ? v : 0.f;
        }

    {
        int kb = t >> 4;
        int c4 = (t & 15) * 4;
        #pragma unroll
        for (int q = 0; q < 4; ++q) {
            int k = kb + 16 * q;
            *(float4*)&Ws[k][c4] = *(const float4*)&W2[(size_t)k * 64 + c4];
        }
    }
    __syncthreads();

    float acc2[4][4] = {};
    #pragma unroll
    for (int kk = 0; kk < 64; ++kk) {
        float4 a = *(float4*)&Hs[kk][ty * 4];
        float4 b = *(float4*)&Ws[kk][tx * 4];
        float av[4] = {a.x, a.y, a.z, a.w};
        float bv[4] = {b.x, b.y, b.z, b.w};
        #pragma unroll
        for (int i = 0; i < 4; ++i)
            #pragma unroll
            for (int j = 0; j < 4; ++j)
                acc2[i][j] += av[i] * bv[j];
    }

    #pragma unroll
    for (int i = 0; i < 4; ++i) {
        int grow = row0 + ty * 4 + i;
        if (grow < nN) {
            float4 o;
            o.x = acc2[i][0] > 0.f ? acc2[i][0] : 0.f;
            o.y = acc2[i][1] > 0.f ? acc2[i][1] : 0.f;
            o.z = acc2[i][2] > 0.f ? acc2[i][2] : 0.f;
            o.w = acc2[i][3] > 0.f ? acc2[i][3] : 0.f;
            *(float4*)&h0[(size_t)grow * 64 + tx * 4] = o;
        }
    }
}

// ---------------------------------------------------------------------------
// CSR build: degree count -> single-block scan -> atomic fill.
// After fill, rowptr[n] holds END offset of node n; start = rowptr[n-1] (0 for n=0).
// ---------------------------------------------------------------------------
__launch_bounds__(256)
__global__ void count_kernel(const int* __restrict__ dst, int* __restrict__ rowptr, int nE)
{
    int e = blockIdx.x * 256 + threadIdx.x;
    if (e < nE) atomicAdd(&rowptr[dst[e]], 1);
}

__launch_bounds__(1024)
__global__ void scan_kernel(int* __restrict__ deg, int nN)
{
    __shared__ int sums[1024];
    const int t = threadIdx.x;
    const int len = (nN + 1023) / 1024;
    const int lo = t * len;
    const int hi = min(nN, lo + len);
    int s = 0;
    for (int i = lo; i < hi; ++i) s += deg[i];
    sums[t] = s;
    __syncthreads();
    for (int d = 1; d < 1024; d <<= 1) {
        int v = (t >= d) ? sums[t - d] : 0;
        __syncthreads();
        sums[t] += v;
        __syncthreads();
    }
    int off = sums[t] - s;  // exclusive prefix of this thread's chunk
    for (int i = lo; i < hi; ++i) {
        int d = deg[i];
        deg[i] = off;
        off += d;
    }
}

__launch_bounds__(256)
__global__ void fill_kernel(const int* __restrict__ src, const int* __restrict__ dst,
                            const float* __restrict__ w,
                            int* __restrict__ rowptr,
                            int* __restrict__ col, float* __restrict__ wgt, int nE)
{
    int e = blockIdx.x * 256 + threadIdx.x;
    if (e >= nE) return;
    int d = dst[e];
    int pos = atomicAdd(&rowptr[d], 1);
    col[pos] = src[e];
    wgt[pos] = w[e];
}

// ---------------------------------------------------------------------------
// Pull-mode SpMM: one wave per dst node. 4 edges in flight (16 lanes x float4
// each), butterfly-reduce across edge groups, single 256B coalesced write.
// ---------------------------------------------------------------------------
__launch_bounds__(256)
__global__ void spmm_pull(const int* __restrict__ rowptr,
                          const int* __restrict__ col,
                          const float* __restrict__ wgt,
                          const float* __restrict__ cur,
                          float* __restrict__ nxt, int nN)
{
    int gid = blockIdx.x * 256 + threadIdx.x;
    int node = gid >> 6;
    if (node >= nN) return;
    int lane = threadIdx.x & 63;
    int g = lane >> 4;   // edge sub-slot 0..3
    int q = lane & 15;   // channel quad

    int beg = (node == 0) ? 0 : rowptr[node - 1];
    int end = rowptr[node];

    float4 acc = make_float4(0.f, 0.f, 0.f, 0.f);
    for (int e = beg + g; e < end; e += 4) {
        int s = col[e];
        float w = wgt[e];
        float4 v = *(const float4*)&cur[(size_t)s * 64 + q * 4];
        acc.x += w * v.x;
        acc.y += w * v.y;
        acc.z += w * v.z;
        acc.w += w * v.w;
    }
    // combine the 4 edge groups (lanes differing in bits 4,5)
    acc.x += __shfl_xor(acc.x, 16); acc.y += __shfl_xor(acc.y, 16);
    acc.z += __shfl_xor(acc.z, 16); acc.w += __shfl_xor(acc.w, 16);
    acc.x += __shfl_xor(acc.x, 32); acc.y += __shfl_xor(acc.y, 32);
    acc.z += __shfl_xor(acc.z, 32); acc.w += __shfl_xor(acc.w, 32);

    if (g == 0)
        *(float4*)&nxt[(size_t)node * 64 + q * 4] = acc;
}

// ---------------------------------------------------------------------------
// Gate-gather: for each requested node i, out[i] (+)= sigmoid(h[idx[i]].wp) * h[idx[i]]
// One wave per index, accumulating directly into d_out.
// ---------------------------------------------------------------------------
__launch_bounds__(256)
__global__ void gate_gather(const float* __restrict__ h,
                            const int* __restrict__ idx,
                            const float* __restrict__ wp,
                            float* __restrict__ out, int nI, int init)
{
    int gid = blockIdx.x * 256 + threadIdx.x;
    int i = gid >> 6;
    if (i >= nI) return;
    int c = gid & 63;
    int n = idx[i];
    float v = h[(size_t)n * 64 + c];
    float s = v * wp[c];
    #pragma unroll
    for (int off = 32; off > 0; off >>= 1)
        s += __shfl_xor(s, off);
    float gate = 1.f / (1.f + __expf(-s));
    float o = gate * v;
    if (init) out[gid] = o;
    else      out[gid] += o;
}

extern "C" void kernel_launch(void* const* d_in, const int* in_sizes, int n_in,
                              void* d_out, int out_size, void* d_ws, size_t ws_size,
                              hipStream_t stream) {
    const float* x    = (const float*)d_in[0];
    const int*   esrc = (const int*)d_in[1];
    const int*   edst = (const int*)d_in[2];
    const float* ew   = (const float*)d_in[3];
    const int*   nidx = (const int*)d_in[4];
    const float* W1   = (const float*)d_in[5];
    const float* W2   = (const float*)d_in[6];
    const float* wp   = (const float*)d_in[7];
    float* out = (float*)d_out;

    const int nN = in_sizes[0] / 512;
    const int nE = in_sizes[1];
    const int nI = in_sizes[4];

    // workspace layout (bytes): bufA 25.6M | bufB 25.6M | rowptr 0.4M | col 6.4M | wgt 6.4M
    float* bufA   = (float*)d_ws;
    float* bufB   = bufA + (size_t)nN * C;
    int*   rowptr = (int*)(bufB + (size_t)nN * C);
    int*   col    = rowptr + nN;
    float* wgt    = (float*)(col + nE);

    // --- CSR build (by dst) ---
    hipMemsetAsync(rowptr, 0, (size_t)nN * sizeof(int), stream);
    count_kernel<<<(nE + 255) / 256, 256, 0, stream>>>(edst, rowptr, nE);
    scan_kernel<<<1, 1024, 0, stream>>>(rowptr, nN);
    fill_kernel<<<(nE + 255) / 256, 256, 0, stream>>>(esrc, edst, ew, rowptr, col, wgt, nE);

    // --- MLP ---
    mlp_kernel<<<(nN + 63) / 64, 256, 0, stream>>>(x, W1, W2, bufA, nN);

    // hop 0 gate directly into out
    gate_gather<<<(nI * 64 + 255) / 256, 256, 0, stream>>>(bufA, nidx, wp, out, nI, 1);

    float* cur = bufA;
    float* nxt = bufB;
    for (int k = 0; k < 10; ++k) {
        spmm_pull<<<((size_t)nN * 64 + 255) / 256, 256, 0, stream>>>(
            rowptr, col, wgt, cur, nxt, nN);
        gate_gather<<<(nI * 64 + 255) / 256, 256, 0, stream>>>(nxt, nidx, wp, out, nI, 0);
        float* tmp = cur; cur = nxt; nxt = tmp;
    }
}